// Round 1
// baseline (174.904 us; speedup 1.0000x reference)
//
#include <hip/hip_runtime.h>

#define DEV __device__ __forceinline__

typedef __bf16 bf16x8 __attribute__((ext_vector_type(8)));
typedef float f32x4 __attribute__((ext_vector_type(4)));

constexpr int TOK = 32768;   // B*N tokens
constexpr int D   = 512;
constexpr int P   = 720;
constexpr float EPS = 1e-5f;

DEV unsigned short f2bf(float f) {
  unsigned u = __float_as_uint(f);
  u += 0x7FFFu + ((u >> 16) & 1u);   // RNE (normals; inputs are finite randoms)
  return (unsigned short)(u >> 16);
}

DEV void g2lds16(const void* g, void* l) {
  __builtin_amdgcn_global_load_lds(
      (__attribute__((address_space(1))) void*)g,
      (__attribute__((address_space(3))) void*)l, 16, 0, 0);
}

// ---------------- W_exp [2][D][P] fp32 -> WT [2][P][D] bf16 -----------------
__global__ void wconv_kernel(const float* __restrict__ W,
                             unsigned short* __restrict__ WT) {
  __shared__ float ls[16][17];
  const int e  = blockIdx.z;
  const int d0 = blockIdx.x * 16, p0 = blockIdx.y * 16;
  const int tx = threadIdx.x, ty = threadIdx.y;
  ls[ty][tx] = W[((size_t)e * D + d0 + ty) * P + p0 + tx];
  __syncthreads();
  WT[((size_t)e * P + p0 + ty) * D + d0 + tx] = f2bf(ls[tx][ty]);
}

// ---------------- classifier: fp32 MLP -> idx[TOK]; also writes x as bf16 ---
__global__ __launch_bounds__(256) void classifier_kernel(
    const float* __restrict__ x,
    const float* __restrict__ W1, const float* __restrict__ b1,
    const float* __restrict__ g1, const float* __restrict__ be1,
    const float* __restrict__ m1, const float* __restrict__ v1,
    const float* __restrict__ W2, const float* __restrict__ b2,
    const float* __restrict__ g2, const float* __restrict__ be2,
    const float* __restrict__ m2, const float* __restrict__ v2,
    const float* __restrict__ W3, const float* __restrict__ b3,
    unsigned short* __restrict__ xb, int* __restrict__ idx_out)
{
  constexpr int TM = 64, BK = 32, LD = TM + 4;   // LD*4 = 272 B, 16B-multiple
  __shared__ __align__(16) float xs[BK][LD];
  __shared__ __align__(16) float h1s[128][LD];
  __shared__ __align__(16) float h2s[32][LD];

  const int tid = threadIdx.x;
  const int t0  = blockIdx.x * TM;

  const int c0  = (tid & 15) * 8;   // 8 cols of layer-1 per thread
  const int tl0 = (tid >> 4) * 4;   // 4 tokens per thread

  const int kc = tid & 7;           // staging: float4 chunk within 32-wide k
  const int tt = tid >> 3;          // staging: token row (0..31), +32 second

  float acc[4][8];
  #pragma unroll
  for (int i = 0; i < 4; ++i)
    #pragma unroll
    for (int j = 0; j < 8; ++j) acc[i][j] = 0.f;

  for (int k0 = 0; k0 < D; k0 += BK) {
    #pragma unroll
    for (int h = 0; h < 2; ++h) {
      const int tr = tt + h * 32;
      float4 v = *reinterpret_cast<const float4*>(
          &x[(size_t)(t0 + tr) * D + k0 + kc * 4]);
      xs[kc * 4 + 0][tr] = v.x;
      xs[kc * 4 + 1][tr] = v.y;
      xs[kc * 4 + 2][tr] = v.z;
      xs[kc * 4 + 3][tr] = v.w;
      ushort4 u;
      u.x = f2bf(v.x); u.y = f2bf(v.y); u.z = f2bf(v.z); u.w = f2bf(v.w);
      *reinterpret_cast<ushort4*>(&xb[(size_t)(t0 + tr) * D + k0 + kc * 4]) = u;
    }
    __syncthreads();
    #pragma unroll
    for (int kk = 0; kk < BK; ++kk) {
      float4 xv = *reinterpret_cast<const float4*>(&xs[kk][tl0]);
      float4 wa = *reinterpret_cast<const float4*>(&W1[(size_t)(k0 + kk) * 128 + c0]);
      float4 wb = *reinterpret_cast<const float4*>(&W1[(size_t)(k0 + kk) * 128 + c0 + 4]);
      const float xr[4] = {xv.x, xv.y, xv.z, xv.w};
      const float wr[8] = {wa.x, wa.y, wa.z, wa.w, wb.x, wb.y, wb.z, wb.w};
      #pragma unroll
      for (int i = 0; i < 4; ++i)
        #pragma unroll
        for (int j = 0; j < 8; ++j)
          acc[i][j] = fmaf(xr[i], wr[j], acc[i][j]);
    }
    __syncthreads();
  }

  // BN1 (eval) + ReLU -> h1s[c][t]
  #pragma unroll
  for (int j = 0; j < 8; ++j) {
    const int c = c0 + j;
    const float A  = g1[c] / sqrtf(v1[c] + EPS);
    const float Bc = (b1[c] - m1[c]) * A + be1[c];
    float4 hv;
    hv.x = fmaxf(0.f, fmaf(acc[0][j], A, Bc));
    hv.y = fmaxf(0.f, fmaf(acc[1][j], A, Bc));
    hv.z = fmaxf(0.f, fmaf(acc[2][j], A, Bc));
    hv.w = fmaxf(0.f, fmaf(acc[3][j], A, Bc));
    *reinterpret_cast<float4*>(&h1s[c][tl0]) = hv;
  }
  __syncthreads();

  // layer 2: per thread 4 tokens x 2 cols
  {
    const int c2 = (tid & 15) * 2;
    const int t2 = (tid >> 4) * 4;
    float a2[4][2] = {{0.f, 0.f}, {0.f, 0.f}, {0.f, 0.f}, {0.f, 0.f}};
    #pragma unroll 4
    for (int j = 0; j < 128; ++j) {
      float4 hv = *reinterpret_cast<const float4*>(&h1s[j][t2]);
      const float w0 = W2[j * 32 + c2];
      const float w1 = W2[j * 32 + c2 + 1];
      const float hr[4] = {hv.x, hv.y, hv.z, hv.w};
      #pragma unroll
      for (int i = 0; i < 4; ++i) {
        a2[i][0] = fmaf(hr[i], w0, a2[i][0]);
        a2[i][1] = fmaf(hr[i], w1, a2[i][1]);
      }
    }
    #pragma unroll
    for (int cc = 0; cc < 2; ++cc) {
      const int c = c2 + cc;
      const float A  = g2[c] / sqrtf(v2[c] + EPS);
      const float Bc = (b2[c] - m2[c]) * A + be2[c];
      float4 hv;
      hv.x = fmaxf(0.f, fmaf(a2[0][cc], A, Bc));
      hv.y = fmaxf(0.f, fmaf(a2[1][cc], A, Bc));
      hv.z = fmaxf(0.f, fmaf(a2[2][cc], A, Bc));
      hv.w = fmaxf(0.f, fmaf(a2[3][cc], A, Bc));
      *reinterpret_cast<float4*>(&h2s[c][t2]) = hv;
    }
  }
  __syncthreads();

  // layer 3 + decision:  idx = (logit > 0)   [== clip(round(sigmoid),0,1)]
  if (tid < TM) {
    float logit = b3[0];
    #pragma unroll
    for (int k = 0; k < 32; ++k)
      logit = fmaf(h2s[k][tid], W3[k], logit);
    idx_out[t0 + tid] = (logit > 0.f) ? 1 : 0;
  }
}

// ---------------- expert GEMM: bf16 MFMA, both experts, per-row select ------
__global__ __launch_bounds__(256) void expert_gemm_kernel(
    const unsigned short* __restrict__ xb,   // [TOK][D] bf16 bits
    const unsigned short* __restrict__ WT,   // [2][P][D] bf16 bits
    const float* __restrict__ b_exp,         // [2][P]
    const int* __restrict__ idx,             // [TOK]
    float* __restrict__ out)                 // [TOK][P]
{
  constexpr int GM = 128, GN = 80, GK = 32;
  __shared__ __align__(16) unsigned short As[GM * GK];      // 8 KB, 64 B rows
  __shared__ __align__(16) unsigned short Bs[2 * GN * GK];  // 10 KB

  const int tid  = threadIdx.x;
  const int wave = tid >> 6;
  const int lane = tid & 63;
  const int t0 = blockIdx.x * GM;
  const int p0 = blockIdx.y * GN;

  f32x4 acc[2][2][5];
  #pragma unroll
  for (int e = 0; e < 2; ++e)
    #pragma unroll
    for (int mf = 0; mf < 2; ++mf)
      #pragma unroll
      for (int nf = 0; nf < 5; ++nf) acc[e][mf][nf] = (f32x4)(0.f);

  // staging geometry: one wave-op = 1024 B = 16 rows of 64 B
  const int srow = lane >> 2;                       // row within 16-row chunk
  const int sswz = (lane & 3) ^ ((srow >> 1) & 3);  // source chunk (XOR swizzle)

  for (int kt = 0; kt < D / GK; ++kt) {
    const int k0 = kt * GK;
    #pragma unroll
    for (int i = 0; i < 5; ++i) {
      const int c = wave + i * 4;
      if (c < 18) {
        if (c < 8) {                                   // A: 8 chunks
          const int row = c * 16 + srow;
          g2lds16(xb + (size_t)(t0 + row) * D + k0 + sswz * 8,
                  (char*)As + c * 1024);
        } else {                                       // B: 2 experts x 5 chunks
          const int cb = c - 8;
          const int e  = (cb >= 5) ? 1 : 0;
          const int bc = cb - e * 5;
          const int pr = bc * 16 + srow;
          g2lds16(WT + ((size_t)e * P + p0 + pr) * D + k0 + sswz * 8,
                  (char*)Bs + e * 5120 + bc * 1024);
        }
      }
    }
    __syncthreads();

    bf16x8 af[2];
    #pragma unroll
    for (int mf = 0; mf < 2; ++mf) {
      const int r  = wave * 32 + mf * 16 + (lane & 15);
      const int ch = (lane >> 4) ^ ((r >> 1) & 3);
      af[mf] = *(const bf16x8*)((const char*)As + r * 64 + ch * 16);
    }
    #pragma unroll
    for (int e = 0; e < 2; ++e) {
      #pragma unroll
      for (int nf = 0; nf < 5; ++nf) {
        const int pr = nf * 16 + (lane & 15);
        const int ch = (lane >> 4) ^ ((pr >> 1) & 3);
        bf16x8 bfrag = *(const bf16x8*)((const char*)Bs + e * 5120 + pr * 64 + ch * 16);
        #pragma unroll
        for (int mf = 0; mf < 2; ++mf)
          acc[e][mf][nf] = __builtin_amdgcn_mfma_f32_16x16x32_bf16(
              af[mf], bfrag, acc[e][mf][nf], 0, 0, 0);
      }
    }
    __syncthreads();
  }

  // epilogue: per-row expert select + bias, store fp32
  const int col = lane & 15;
  const int rg  = lane >> 4;
  int er[2][4];
  #pragma unroll
  for (int mf = 0; mf < 2; ++mf)
    #pragma unroll
    for (int j = 0; j < 4; ++j)
      er[mf][j] = idx[t0 + wave * 32 + mf * 16 + rg * 4 + j];

  #pragma unroll
  for (int nf = 0; nf < 5; ++nf) {
    const int p = p0 + nf * 16 + col;
    const float be0 = b_exp[p];
    const float be1v = b_exp[P + p];
    #pragma unroll
    for (int mf = 0; mf < 2; ++mf) {
      #pragma unroll
      for (int j = 0; j < 4; ++j) {
        const int row = wave * 32 + mf * 16 + rg * 4 + j;
        const float v = er[mf][j] ? (acc[1][mf][nf][j] + be1v)
                                  : (acc[0][mf][nf][j] + be0);
        out[(size_t)(t0 + row) * P + p] = v;
      }
    }
  }
}

extern "C" void kernel_launch(void* const* d_in, const int* in_sizes, int n_in,
                              void* d_out, int out_size, void* d_ws, size_t ws_size,
                              hipStream_t stream) {
  const float* x     = (const float*)d_in[0];
  const float* W_exp = (const float*)d_in[1];
  const float* b_exp = (const float*)d_in[2];
  const float* W1 = (const float*)d_in[3];
  const float* b1 = (const float*)d_in[4];
  const float* g1 = (const float*)d_in[5];
  const float* be1 = (const float*)d_in[6];
  const float* m1 = (const float*)d_in[7];
  const float* v1 = (const float*)d_in[8];
  const float* W2 = (const float*)d_in[9];
  const float* b2 = (const float*)d_in[10];
  const float* g2 = (const float*)d_in[11];
  const float* be2 = (const float*)d_in[12];
  const float* m2 = (const float*)d_in[13];
  const float* v2 = (const float*)d_in[14];
  const float* W3 = (const float*)d_in[15];
  const float* b3 = (const float*)d_in[16];
  float* out = (float*)d_out;

  unsigned short* xb = (unsigned short*)d_ws;                       // 32 MB
  unsigned short* WT = (unsigned short*)((char*)d_ws + (size_t)TOK * D * 2);
  int* idx = (int*)((char*)d_ws + (size_t)TOK * D * 2 + (size_t)2 * P * D * 2);

  hipLaunchKernelGGL(wconv_kernel, dim3(D / 16, P / 16, 2), dim3(16, 16),
                     0, stream, W_exp, WT);
  hipLaunchKernelGGL(classifier_kernel, dim3(TOK / 64), dim3(256), 0, stream,
                     x, W1, b1, g1, be1, m1, v1, W2, b2, g2, be2, m2, v2, W3, b3,
                     xb, idx);
  hipLaunchKernelGGL(expert_gemm_kernel, dim3(TOK / 128, P / 80), dim3(256),
                     0, stream, xb, WT, b_exp, idx, out);
}